// Round 10
// baseline (225.973 us; speedup 1.0000x reference)
//
#include <hip/hip_runtime.h>
#include <math.h>

#define Bn 32
#define Nn 2000
#define En 32000
#define Vn 100000
#define Dn 128
#define Rn 39
#define Kn 8

#define SUBS 8
#define NPS (Nn / SUBS)   // 250 nodes per sub-block
#define EQ (En / 4)       // 8000 edge-quads per graph
#define GB 8              // gather blocks per graph
#define GW 16             // waves per gather block (GB*GW = 128 waves/graph)
#define WPG (GB * GW)
#define TPB 1024

// Workspace layout (no aliasing):
//   [ 0)         : inv     float[B*E]         = 4,096,000
//   [4,096,000)  : a       float[B*N*K]       = 2,048,000
//   [6,144,000)  : partial float[B*GB*9*128]  = 1,179,648
//   [7,323,648)  : ticket  int[B]             = 128
//
// 3 dispatches (R8 lesson: no grid.sync / no spin-waits in this harness —
// only the non-blocking "last arriver finalizes" ticket pattern is safe).
// blockIdx.x = graph everywhere -> XCD affinity (R2 evidence: 9x fetch cut).

// K1: fused cnt+inv. 8 blocks/graph own dst-ranges. Pass 1: LDS (dst,rel)
// histogram. Pass 2: re-scan (L2-hot) edges, write inv[e]=1/cnt for owned
// edges (each edge owned by exactly one block). cnt never touches global.
__global__ __launch_bounds__(TPB) void cntinv_kernel(const int* __restrict__ edge_index,
                                                     const int* __restrict__ edge_type,
                                                     float* __restrict__ inv) {
    int b = blockIdx.x, sub = blockIdx.y;
    int s0 = sub * NPS;
    __shared__ int loc[NPS * Rn];                 // 39 KB
    for (int i = threadIdx.x; i < NPS * Rn; i += TPB) loc[i] = 0;
    __syncthreads();
    const int4* dst4 = (const int4*)(edge_index + (b * 2 + 1) * En);
    const int4* et4  = (const int4*)(edge_type + b * En);
    for (int q = threadIdx.x; q < EQ; q += TPB) {
        int4 d = dst4[q]; int4 t = et4[q]; int x;
        x = d.x - s0; if ((unsigned)x < NPS) atomicAdd(&loc[x * Rn + t.x], 1);
        x = d.y - s0; if ((unsigned)x < NPS) atomicAdd(&loc[x * Rn + t.y], 1);
        x = d.z - s0; if ((unsigned)x < NPS) atomicAdd(&loc[x * Rn + t.z], 1);
        x = d.w - s0; if ((unsigned)x < NPS) atomicAdd(&loc[x * Rn + t.w], 1);
    }
    __syncthreads();
    float* ivb = inv + (size_t)b * En;
    for (int q = threadIdx.x; q < EQ; q += TPB) {
        int4 d = dst4[q]; int4 t = et4[q];
        int e = 4 * q, x;
        x = d.x - s0; if ((unsigned)x < NPS) ivb[e]     = 1.0f / (float)loc[x * Rn + t.x];
        x = d.y - s0; if ((unsigned)x < NPS) ivb[e + 1] = 1.0f / (float)loc[x * Rn + t.y];
        x = d.z - s0; if ((unsigned)x < NPS) ivb[e + 2] = 1.0f / (float)loc[x * Rn + t.z];
        x = d.w - s0; if ((unsigned)x < NPS) ivb[e + 3] = 1.0f / (float)loc[x * Rn + t.w];
    }
}

// K2: 8 blocks/graph own src-ranges. Streaming scan, ONE LDS atomic/edge into
// s[src][t] (stride 39, coprime to 32 banks), then a[n][k] = s @ comp.
// Also zeroes the gather tickets (ws is re-poisoned before every launch).
__global__ __launch_bounds__(TPB) void a_kernel(const int* __restrict__ edge_index,
                                                const int* __restrict__ edge_type,
                                                const float* __restrict__ inv,
                                                const float* __restrict__ comp,
                                                float* __restrict__ a,
                                                int* __restrict__ ticket) {
    int b = blockIdx.x, sub = blockIdx.y;
    if (sub == 0 && threadIdx.x == 0) ticket[b] = 0;
    int s0 = sub * NPS;
    __shared__ float s[NPS * Rn];                 // 39 KB
    __shared__ float comp_l[Rn * Kn];
    for (int i = threadIdx.x; i < NPS * Rn; i += TPB) s[i] = 0.0f;
    if (threadIdx.x < Rn * Kn) comp_l[threadIdx.x] = comp[threadIdx.x];
    __syncthreads();
    const int4*   src4 = (const int4*)(edge_index + (b * 2 + 0) * En);
    const int4*   et4  = (const int4*)(edge_type + b * En);
    const float4* iv4  = (const float4*)(inv + (size_t)b * En);
    for (int q = threadIdx.x; q < EQ; q += TPB) {
        int4 sv = src4[q]; int4 tv = et4[q]; float4 iv = iv4[q]; int x;
        x = sv.x - s0; if ((unsigned)x < NPS) atomicAdd(&s[x * Rn + tv.x], iv.x);
        x = sv.y - s0; if ((unsigned)x < NPS) atomicAdd(&s[x * Rn + tv.y], iv.y);
        x = sv.z - s0; if ((unsigned)x < NPS) atomicAdd(&s[x * Rn + tv.z], iv.z);
        x = sv.w - s0; if ((unsigned)x < NPS) atomicAdd(&s[x * Rn + tv.w], iv.w);
    }
    __syncthreads();
    float* g = a + ((size_t)b * Nn + s0) * Kn;
    for (int i = threadIdx.x; i < NPS * Kn; i += TPB) {
        int n = i >> 3, k = i & 7;
        float acc = 0.0f;
        const float* srow = &s[n * Rn];
        for (int t = 0; t < Rn; t++) acc += srow[t] * comp_l[t * Kn + k];
        g[i] = acc;
    }
}

// K3: gather + ticket-gated finalize. 8 blocks x 1024 threads per graph.
// Each of 16 waves gathers ~16 embedding rows (unroll-4 ILP), block-combines
// in LDS, stores one 9x128 partial. Last-arriving block of the graph (ticket)
// reduces the 8 L2-hot partials, does 9 matvecs 1152-wide, L2-normalizes.
__global__ __launch_bounds__(TPB) void gather_final_kernel(
    const int* __restrict__ node_ids, const float* __restrict__ emb,
    const float* __restrict__ a, const float* __restrict__ root,
    const float* __restrict__ bases, const float* __restrict__ bias,
    float* partial, int* ticket, float* __restrict__ out)
{
    __shared__ float red[GW * 9 * Dn];            // 73,728 B
    __shared__ int isLast;
    int b = blockIdx.x, sub = blockIdx.y;
    int tid = threadIdx.x, lane = tid & 63, wv = tid >> 6;
    int W = sub * GW + wv;                        // wave id in [0, WPG)

    float acc[18];
#pragma unroll
    for (int k = 0; k < 18; k++) acc[k] = 0.0f;
    const int*   nb = node_ids + b * Nn;
    const float* ab = a + (size_t)b * Nn * Kn;
    for (int n0 = W; n0 < Nn; n0 += 4 * WPG) {
        bool   has[4];
        int    nn[4];
        float2 v[4];
        float4 a0[4], a1[4];
#pragma unroll
        for (int i = 0; i < 4; i++) {
            int n = n0 + i * WPG;
            has[i] = n < Nn;
            nn[i]  = has[i] ? n : n0;
        }
#pragma unroll
        for (int i = 0; i < 4; i++) {
            int nid = nb[nn[i]];
            v[i] = has[i] ? ((const float2*)(emb + (size_t)nid * Dn))[lane]
                          : make_float2(0.f, 0.f);
            const float4* ar = (const float4*)(ab + (size_t)nn[i] * Kn);
            a0[i] = ar[0]; a1[i] = ar[1];
        }
#pragma unroll
        for (int i = 0; i < 4; i++) {
            float w[9] = {a0[i].x, a0[i].y, a0[i].z, a0[i].w,
                          a1[i].x, a1[i].y, a1[i].z, a1[i].w, 1.0f};
#pragma unroll
            for (int k = 0; k < 9; k++) {
                acc[2 * k]     += w[k] * v[i].x;
                acc[2 * k + 1] += w[k] * v[i].y;
            }
        }
    }
#pragma unroll
    for (int k = 0; k < 9; k++)
        ((float2*)&red[(wv * 9 + k) * Dn])[lane] = make_float2(acc[2 * k], acc[2 * k + 1]);
    __syncthreads();

    // block combine: 1152 outputs, each a sum of 16 wave slices
    float* gp = partial + ((size_t)(b * GB + sub)) * 9 * Dn;
    for (int i = tid; i < 9 * Dn; i += TPB) {
        float s = 0.0f;
#pragma unroll
        for (int w = 0; w < GW; w++) s += red[w * 9 * Dn + i];
        gp[i] = s;
    }
    __threadfence();                              // publish partial (release)
    if (tid == 0) {
        int old = atomicAdd(&ticket[b], 1);
        isLast = ((old & (GB - 1)) == (GB - 1));  // replay-idempotent
    }
    __syncthreads();
    if (!isLast) return;                          // non-blocking: no waiting
    __threadfence();                              // acquire side

    // reduce the graph's 8 partials (just written, L2-hot, same XCD)
    volatile const float* pb = partial + (size_t)b * GB * 9 * Dn;
    for (int i = tid; i < 9 * Dn; i += TPB) {
        float s = 0.0f;
#pragma unroll
        for (int c = 0; c < GB; c++) s += pb[c * 9 * Dn + i];
        red[i] = s;                               // ts[9][128]
    }
    __syncthreads();

    // 9 matvecs, 1152 independent (m,d) units
    for (int u = tid; u < 9 * Dn; u += TPB) {
        int m = u >> 7, d = u & (Dn - 1);
        const float* M  = (m == 8) ? root : bases + (size_t)m * Dn * Dn;
        const float* ts = &red[m * Dn];
        float g = 0.0f;
        for (int j = 0; j < Dn; j++) g += ts[j] * M[j * Dn + d];
        red[9 * Dn + u] = g;
    }
    __syncthreads();

    // g[d] = N*bias + sum_m; then L2-norm over 128 dims (2 waves via LDS)
    float g = 0.0f;
    if (tid < Dn) {
        g = (float)Nn * bias[tid];
#pragma unroll
        for (int m = 0; m < 9; m++) g += red[9 * Dn + m * Dn + tid];
        red[18 * Dn + tid] = g;
    }
    float ss = (tid < Dn) ? g * g : 0.0f;
    if (tid < 128) {
#pragma unroll
        for (int off = 32; off > 0; off >>= 1) ss += __shfl_down(ss, off, 64);
        if ((tid & 63) == 0) red[19 * Dn + (tid >> 6)] = ss;
    }
    __syncthreads();
    if (tid < Dn) {
        float nrm = sqrtf(red[19 * Dn] + red[19 * Dn + 1]);
        out[b * Dn + tid] = red[18 * Dn + tid] / fmaxf(nrm, 1e-5f);
    }
}

extern "C" void kernel_launch(void* const* d_in, const int* in_sizes, int n_in,
                              void* d_out, int out_size, void* d_ws, size_t ws_size,
                              hipStream_t stream) {
    const int*   node_ids   = (const int*)d_in[0];
    const int*   edge_index = (const int*)d_in[1];
    const int*   edge_type  = (const int*)d_in[2];
    const float* embedding  = (const float*)d_in[3];
    const float* bases      = (const float*)d_in[4];
    const float* comp       = (const float*)d_in[5];
    const float* root       = (const float*)d_in[6];
    const float* bias       = (const float*)d_in[7];
    float*       out        = (float*)d_out;

    char* w = (char*)d_ws;
    float* inv     = (float*)(w + 0);
    float* a       = (float*)(w + 4096000);
    float* partial = (float*)(w + 6144000);
    int*   ticket  = (int*)  (w + 7323648);

    cntinv_kernel      <<<dim3(Bn, SUBS), TPB, 0, stream>>>(edge_index, edge_type, inv);
    a_kernel           <<<dim3(Bn, SUBS), TPB, 0, stream>>>(edge_index, edge_type, inv, comp, a, ticket);
    gather_final_kernel<<<dim3(Bn, GB),   TPB, 0, stream>>>(node_ids, embedding, a, root,
                                                            bases, bias, partial, ticket, out);
}

// Round 13
// 156.051 us; speedup vs baseline: 1.4481x; 1.4481x over previous
//
#include <hip/hip_runtime.h>
#include <math.h>

#define Bn 32
#define Nn 2000
#define En 32000
#define Vn 100000
#define Dn 128
#define Rn 39
#define Kn 8

#define SUBS 8
#define NPS (Nn / SUBS)   // 250 dst nodes per sub-block
#define WPG 128           // gather waves (= partial chunks) per graph
#define EQ (En / 4)       // 8000 edge-quads per graph

// Workspace layout (no aliasing):
//   [ 0)          : inv     float[B*E]          =  4,096,000
//   [ 4,096,000)  : a       float[B*N*K]        =  2,048,000
//   [ 6,144,000)  : partial float[B*WPG*9*128]  = 18,874,368
//   [25,018,368)  : gmat    float[B*9*128]      =    147,456
//
// R12 = R7 VERBATIM (proven 156.2us): control run to split "final_kernel
// kills container" vs "infra outage" after R10/R11 double-failures.
// blockIdx.x = graph everywhere -> XCD affinity (R2 evidence: 9x fetch cut).

// K1: fused cnt+inv. 8 blocks/graph own dst-ranges. Pass 1: LDS histogram of
// (dst,rel) over the block's range. Pass 2: re-scan (L2-hot) edges, write
// inv[e]=1/cnt for owned edges (each edge owned by exactly one block).
__global__ __launch_bounds__(1024) void cntinv_kernel(const int* __restrict__ edge_index,
                                                      const int* __restrict__ edge_type,
                                                      float* __restrict__ inv) {
    int b = blockIdx.x, sub = blockIdx.y;
    int s0 = sub * NPS;
    __shared__ int loc[NPS * Rn];                 // 9750 ints = 39 KB
    for (int i = threadIdx.x; i < NPS * Rn; i += 1024) loc[i] = 0;
    __syncthreads();
    const int4* dst4 = (const int4*)(edge_index + (b * 2 + 1) * En);
    const int4* et4  = (const int4*)(edge_type + b * En);
    for (int q = threadIdx.x; q < EQ; q += 1024) {
        int4 d = dst4[q];
        int4 t = et4[q];
        int x;
        x = d.x - s0; if ((unsigned)x < NPS) atomicAdd(&loc[x * Rn + t.x], 1);
        x = d.y - s0; if ((unsigned)x < NPS) atomicAdd(&loc[x * Rn + t.y], 1);
        x = d.z - s0; if ((unsigned)x < NPS) atomicAdd(&loc[x * Rn + t.z], 1);
        x = d.w - s0; if ((unsigned)x < NPS) atomicAdd(&loc[x * Rn + t.w], 1);
    }
    __syncthreads();
    float* ivb = inv + (size_t)b * En;
    for (int q = threadIdx.x; q < EQ; q += 1024) {
        int4 d = dst4[q];
        int4 t = et4[q];
        int e = 4 * q, x;
        x = d.x - s0; if ((unsigned)x < NPS) ivb[e]     = 1.0f / (float)loc[x * Rn + t.x];
        x = d.y - s0; if ((unsigned)x < NPS) ivb[e + 1] = 1.0f / (float)loc[x * Rn + t.y];
        x = d.z - s0; if ((unsigned)x < NPS) ivb[e + 2] = 1.0f / (float)loc[x * Rn + t.z];
        x = d.w - s0; if ((unsigned)x < NPS) ivb[e + 3] = 1.0f / (float)loc[x * Rn + t.w];
    }
}

// K2: 8 blocks/graph own src-ranges. Pure streaming scan (src,et,inv all
// sequential), ONE LDS atomic/edge into s[src][t] (stride 39, coprime to 32
// banks -> conflict-free), then a[n][k] = s @ comp.
__global__ __launch_bounds__(1024) void a_kernel(const int* __restrict__ edge_index,
                                                 const int* __restrict__ edge_type,
                                                 const float* __restrict__ inv,
                                                 const float* __restrict__ comp,
                                                 float* __restrict__ a) {
    int b = blockIdx.x, sub = blockIdx.y;
    int s0 = sub * NPS;
    __shared__ float s[NPS * Rn];                 // 39 KB
    __shared__ float comp_l[Rn * Kn];
    for (int i = threadIdx.x; i < NPS * Rn; i += 1024) s[i] = 0.0f;
    if (threadIdx.x < Rn * Kn) comp_l[threadIdx.x] = comp[threadIdx.x];
    __syncthreads();
    const int4*   src4 = (const int4*)(edge_index + (b * 2 + 0) * En);
    const int4*   et4  = (const int4*)(edge_type + b * En);
    const float4* iv4  = (const float4*)(inv + (size_t)b * En);
    for (int q = threadIdx.x; q < EQ; q += 1024) {
        int4 sv = src4[q];
        int4 tv = et4[q];
        float4 iv = iv4[q];
        int x;
        x = sv.x - s0; if ((unsigned)x < NPS) atomicAdd(&s[x * Rn + tv.x], iv.x);
        x = sv.y - s0; if ((unsigned)x < NPS) atomicAdd(&s[x * Rn + tv.y], iv.y);
        x = sv.z - s0; if ((unsigned)x < NPS) atomicAdd(&s[x * Rn + tv.z], iv.z);
        x = sv.w - s0; if ((unsigned)x < NPS) atomicAdd(&s[x * Rn + tv.w], iv.w);
    }
    __syncthreads();
    float* g = a + ((size_t)b * Nn + s0) * Kn;
    for (int i = threadIdx.x; i < NPS * Kn; i += 1024) {   // 2000 outputs
        int n = i >> 3, k = i & 7;
        float acc = 0.0f;
        const float* srow = &s[n * Rn];
        for (int t = 0; t < Rn; t++) acc += srow[t] * comp_l[t * Kn + k];
        g[i] = acc;
    }
}

// K3: wave-autonomous gather. Each of 128 waves/graph owns node set
// {n : n mod 128 == W} (~16 nodes), unroll-4 row loads for MLP, and writes its
// own partial chunk [W][9][128] with coalesced float2 stores. No LDS, no syncs.
__global__ __launch_bounds__(256) void gather_kernel(const int* __restrict__ node_ids,
                                                     const float* __restrict__ emb,
                                                     const float* __restrict__ a,
                                                     float* __restrict__ partial) {
    int b = blockIdx.x;
    int lane = threadIdx.x & 63, wv = threadIdx.x >> 6;
    int W = blockIdx.y * 4 + wv;                  // wave id in [0, WPG)
    float acc[18];
#pragma unroll
    for (int k = 0; k < 18; k++) acc[k] = 0.0f;
    const int*   nb = node_ids + b * Nn;
    const float* ab = a + (size_t)b * Nn * Kn;
    for (int n0 = W; n0 < Nn; n0 += 4 * WPG) {
        bool   has[4];
        int    nn[4];
        float2 v[4];
        float4 a0[4], a1[4];
#pragma unroll
        for (int i = 0; i < 4; i++) {
            int n = n0 + i * WPG;
            has[i] = n < Nn;
            nn[i]  = has[i] ? n : n0;
        }
#pragma unroll
        for (int i = 0; i < 4; i++) {
            int nid = nb[nn[i]];
            v[i] = has[i] ? ((const float2*)(emb + (size_t)nid * Dn))[lane]
                          : make_float2(0.f, 0.f);
            const float4* ar = (const float4*)(ab + (size_t)nn[i] * Kn);
            a0[i] = ar[0]; a1[i] = ar[1];
        }
#pragma unroll
        for (int i = 0; i < 4; i++) {
            float w[9] = {a0[i].x, a0[i].y, a0[i].z, a0[i].w,
                          a1[i].x, a1[i].y, a1[i].z, a1[i].w, 1.0f};
#pragma unroll
            for (int k = 0; k < 9; k++) {
                acc[2 * k]     += w[k] * v[i].x;
                acc[2 * k + 1] += w[k] * v[i].y;
            }
        }
    }
    float2* gp = (float2*)(partial + ((size_t)b * WPG + W) * 9 * Dn);
#pragma unroll
    for (int k = 0; k < 9; k++)
        gp[k * 64 + lane] = make_float2(acc[2 * k], acc[2 * k + 1]);
}

// K4: one block per (graph, matrix m): reduce 128 chunks (d-coalesced,
// unroll-4 ILP), then m<8 -> bases[m] @ t_m ; m==8 -> root @ s.
__global__ __launch_bounds__(256) void matvec_kernel(const float* __restrict__ partial,
                                                     const float* __restrict__ root,
                                                     const float* __restrict__ bases,
                                                     float* __restrict__ gmat) {
    int b = blockIdx.x, m = blockIdx.y;
    int d = threadIdx.x & (Dn - 1), h = threadIdx.x >> 7;
    __shared__ float ts[Dn];
    __shared__ float tsh[2][Dn];
    const float* p = partial + (size_t)b * WPG * 9 * Dn + m * Dn + d;
    float s0 = 0.f, s1 = 0.f, s2 = 0.f, s3 = 0.f;
    for (int c = h; c < WPG; c += 8) {            // 16 iters x 4 accumulators
        s0 += p[(size_t)(c    ) * 9 * Dn];
        s1 += p[(size_t)(c + 2) * 9 * Dn];
        s2 += p[(size_t)(c + 4) * 9 * Dn];
        s3 += p[(size_t)(c + 6) * 9 * Dn];
    }
    tsh[h][d] = (s0 + s1) + (s2 + s3);
    __syncthreads();
    if (h == 0) ts[d] = tsh[0][d] + tsh[1][d];
    __syncthreads();
    const float* M = (m == 8) ? root : bases + (size_t)m * Dn * Dn;
    float g = 0.0f;
    for (int j = h * 64; j < h * 64 + 64; j++) g += ts[j] * M[j * Dn + d];
    __syncthreads();
    tsh[h][d] = g;
    __syncthreads();
    if (h == 0) gmat[((size_t)b * 9 + m) * Dn + d] = tsh[0][d] + tsh[1][d];
}

// K5: sum the 9 matvec outputs, add bias term, L2-normalize.
__global__ __launch_bounds__(128) void norm_kernel(const float* __restrict__ gmat,
                                                   const float* __restrict__ bias,
                                                   float* __restrict__ out) {
    int b = blockIdx.x, d = threadIdx.x;
    float g = (float)Nn * bias[d];
    const float* gb = gmat + (size_t)b * 9 * Dn + d;
#pragma unroll
    for (int m = 0; m < 9; m++) g += gb[m * Dn];
    float ss = g * g;
#pragma unroll
    for (int off = 32; off > 0; off >>= 1) ss += __shfl_down(ss, off, 64);
    __shared__ float s2[2];
    if ((threadIdx.x & 63) == 0) s2[threadIdx.x >> 6] = ss;
    __syncthreads();
    float nrm = sqrtf(s2[0] + s2[1]);
    out[b * Dn + d] = g / fmaxf(nrm, 1e-5f);
}

extern "C" void kernel_launch(void* const* d_in, const int* in_sizes, int n_in,
                              void* d_out, int out_size, void* d_ws, size_t ws_size,
                              hipStream_t stream) {
    const int*   node_ids   = (const int*)d_in[0];
    const int*   edge_index = (const int*)d_in[1];
    const int*   edge_type  = (const int*)d_in[2];
    const float* embedding  = (const float*)d_in[3];
    const float* bases      = (const float*)d_in[4];
    const float* comp       = (const float*)d_in[5];
    const float* root       = (const float*)d_in[6];
    const float* bias       = (const float*)d_in[7];
    float*       out        = (float*)d_out;

    char* w = (char*)d_ws;
    float* inv     = (float*)(w + 0);
    float* a       = (float*)(w + 4096000);
    float* partial = (float*)(w + 6144000);
    float* gmat    = (float*)(w + 25018368);

    cntinv_kernel<<<dim3(Bn, SUBS),    1024, 0, stream>>>(edge_index, edge_type, inv);
    a_kernel     <<<dim3(Bn, SUBS),    1024, 0, stream>>>(edge_index, edge_type, inv, comp, a);
    gather_kernel<<<dim3(Bn, WPG / 4), 256,  0, stream>>>(node_ids, embedding, a, partial);
    matvec_kernel<<<dim3(Bn, 9),       256,  0, stream>>>(partial, root, bases, gmat);
    norm_kernel  <<<Bn, 128, 0, stream>>>(gmat, bias, out);
}